// Round 10
// baseline (698.833 us; speedup 1.0000x reference)
//
#include <hip/hip_runtime.h>
#include <math.h>

typedef float  f32x4  __attribute__((ext_vector_type(4)));
typedef short  bf16x8 __attribute__((ext_vector_type(8)));

__device__ __forceinline__ ushort f2bf(float f) {
    unsigned u = __float_as_uint(f);
    unsigned r = (u + 0x7fffu + ((u >> 16) & 1u)) >> 16;
    return (ushort)r;
}
__device__ __forceinline__ float bf2f(ushort u) {
    return __uint_as_float(((unsigned)u) << 16);
}
__device__ __forceinline__ float fast_tanh(float x) {
    float e = __expf(2.f * x);
    return 1.f - 2.f / (e + 1.f);
}

// ---------------------------------------------------------------------------
// Generic weight packer: w[oc][ic][3][3] fp32 -> Wp[kb][t][ocp][32] bf16
// ---------------------------------------------------------------------------
__global__ __launch_bounds__(256) void packw_k(
    const float* __restrict__ w, ushort* __restrict__ dst,
    int OCpad, int OCreal, int Cin, int nkb)
{
    int i = blockIdx.x * 256 + threadIdx.x;
    int total = nkb * 9 * OCpad * 32;
    if (i >= total) return;
    int ic32 = i & 31;
    int oc = (i >> 5) % OCpad;
    int t  = (i / (32 * OCpad)) % 9;
    int kb = i / (32 * OCpad * 9);
    int gic = kb * 32 + ic32;
    float v = 0.f;
    if (oc < OCreal && gic < Cin) v = w[((size_t)oc * Cin + gic) * 9 + t];
    dst[i] = f2bf(v);
}

// ---------------------------------------------------------------------------
// Multi-row MFMA 3x3 conv for big maps. Block = 16x16 tile, 4 waves; wave
// owns 4 output rows. Per kx: 6 A-row-frags feed all 3 ky taps (in-register
// reuse -> load:MFMA 1:2.7 at OCB=64, vs 1:1 in r9 -> latency-bound fix).
// ---------------------------------------------------------------------------
template<int OCB, int NKB, int ACT, int OUTMODE>
__global__ __launch_bounds__(256, 3) void gconv_mr(
    const ushort* __restrict__ s0, int n0,
    const ushort* __restrict__ s1, int n1,
    const ushort* __restrict__ Wp, const float* __restrict__ bias,
    void* __restrict__ outp, int H, int W)
{
    constexpr int NB = OCB / 16;
    const int n  = blockIdx.z;
    const int x0 = blockIdx.x * 16, y0 = blockIdx.y * 16;
    const int tid = threadIdx.x;
    const int wid = tid >> 6, lane = tid & 63;
    const int lm = lane & 15, kg = lane >> 4, k0 = kg * 8;
    const int ry = y0 + 4 * wid;                    // wave's first output row
    const bool edge = (x0 == 0) || (x0 + 16 >= W) || (ry == 0) || (ry + 4 >= H);
    const int ntot = n0 + n1;
    const size_t HW = (size_t)H * W;

    const ushort* bptr[NKB];
    int bstr[NKB];
    bool bpad[NKB];
#pragma unroll
    for (int kb = 0; kb < NKB; kb++) {
        int gch = kb * 32 + k0;
        if (gch < n0)        { bptr[kb] = s0 + HW * (size_t)(n * n0) + gch;        bstr[kb] = n0; bpad[kb] = false; }
        else if (gch < ntot) { bptr[kb] = s1 + HW * (size_t)(n * n1) + (gch - n0); bstr[kb] = n1; bpad[kb] = false; }
        else                 { bptr[kb] = s0; bstr[kb] = 0; bpad[kb] = true; }
    }

    f32x4 acc[4][NB];
#pragma unroll
    for (int m = 0; m < 4; m++)
#pragma unroll
        for (int b = 0; b < NB; b++) acc[m][b] = (f32x4){0.f, 0.f, 0.f, 0.f};

#pragma unroll
    for (int kb = 0; kb < NKB; kb++) {
#pragma unroll
        for (int kx = 0; kx < 3; kx++) {
            // 6 A-row fragments: rows ry-1 .. ry+4 at column window kx
            bf16x8 ar[6];
            const int xl = x0 + lm + kx - 1;
#pragma unroll
            for (int r6 = 0; r6 < 6; r6++) {
                int row = ry + r6 - 1;
                bf16x8 z = (bf16x8){0,0,0,0,0,0,0,0};
                if (!bpad[kb] && (!edge || (row >= 0 && row < H && xl >= 0 && xl < W)))
                    z = *(const bf16x8*)&bptr[kb][((size_t)(row * W + xl)) * bstr[kb]];
                ar[r6] = z;
            }
            // taps: ky reuses ar[m+ky]
#pragma unroll
            for (int ky = 0; ky < 3; ky++) {
                bf16x8 wf[NB];
#pragma unroll
                for (int nb = 0; nb < NB; nb++)
                    wf[nb] = *(const bf16x8*)&Wp[(((kb * 9) + ky * 3 + kx) * OCB + nb * 16 + lm) * 32 + k0];
#pragma unroll
                for (int nb = 0; nb < NB; nb++)
#pragma unroll
                    for (int m = 0; m < 4; m++)
                        acc[m][nb] = __builtin_amdgcn_mfma_f32_16x16x32_bf16(ar[m + ky], wf[nb], acc[m][nb], 0, 0, 0);
            }
        }
    }

    if constexpr (OUTMODE == 0) {
        float* outf = (float*)outp;
#pragma unroll
        for (int m = 0; m < 4; m++) {
            int y = ry + m;
            int x = x0 + kg * 4;
#pragma unroll
            for (int nb = 0; nb < NB; nb++) {
                int oc = nb * 16 + lm;
                float bv = bias[oc];
                float r0 = acc[m][nb][0] + bv, r1 = acc[m][nb][1] + bv;
                float r2 = acc[m][nb][2] + bv, r3 = acc[m][nb][3] + bv;
                if (ACT == 1) { r0=fmaxf(r0,0.f); r1=fmaxf(r1,0.f); r2=fmaxf(r2,0.f); r3=fmaxf(r3,0.f); }
                if (ACT == 2) { r0=fast_tanh(r0); r1=fast_tanh(r1); r2=fast_tanh(r2); r3=fast_tanh(r3); }
                float4 o; o.x=r0; o.y=r1; o.z=r2; o.w=r3;
                *(float4*)&outf[(((size_t)n * OCB + oc) * H + y) * W + x] = o;
            }
        }
    } else {
        ushort* outb = (ushort*)outp;
        __shared__ ushort Ls[16 * 16 * OCB];
#pragma unroll
        for (int m = 0; m < 4; m++) {
            int yy = 4 * wid + m;
#pragma unroll
            for (int nb = 0; nb < NB; nb++) {
                int oc = nb * 16 + lm;
                float bv = bias[oc];
#pragma unroll
                for (int r = 0; r < 4; r++) {
                    float v = acc[m][nb][r] + bv;
                    if (ACT == 1) v = fmaxf(v, 0.f);
                    if (ACT == 2) v = fast_tanh(v);
                    Ls[(yy * 16 + kg * 4 + r) * OCB + oc] = f2bf(v);
                }
            }
        }
        __syncthreads();
        constexpr int NQ = OCB / 8;     // chunks of 2048 ushorts
#pragma unroll
        for (int q = 0; q < NQ; q++) {
            int off = q * 2048 + tid * 8;
            int p = off / OCB, wv = off % OCB;
            int yy = p >> 4, xx = p & 15;
            *(bf16x8*)&outb[((size_t)((n * H + y0 + yy)) * W + x0 + xx) * OCB + wv] =
                *(const bf16x8*)&Ls[off];
        }
    }
}

// ---------------------------------------------------------------------------
// w11 multi-row: A NHWC64 @512^2 -> out [2][3][512][512] fp32, relu.
// ---------------------------------------------------------------------------
__global__ __launch_bounds__(256, 3) void gconv11_mr(
    const ushort* __restrict__ A, const ushort* __restrict__ Wp,
    const float* __restrict__ bias, float* __restrict__ out)
{
    const int n  = blockIdx.z;
    const int x0 = blockIdx.x * 16, y0 = blockIdx.y * 16;
    const int tid = threadIdx.x;
    const int wid = tid >> 6, lane = tid & 63;
    const int lm = lane & 15, kg = lane >> 4, k0 = kg * 8;
    const int ry = y0 + 4 * wid;
    const bool edge = (x0 == 0) || (x0 + 16 >= 512) || (ry == 0) || (ry + 4 >= 512);
    const size_t nbase = (size_t)n * 262144 * 64;

    f32x4 acc[4];
#pragma unroll
    for (int m = 0; m < 4; m++) acc[m] = (f32x4){0.f,0.f,0.f,0.f};

#pragma unroll
    for (int kb = 0; kb < 2; kb++) {
#pragma unroll
        for (int kx = 0; kx < 3; kx++) {
            bf16x8 ar[6];
            const int xl = x0 + lm + kx - 1;
#pragma unroll
            for (int r6 = 0; r6 < 6; r6++) {
                int row = ry + r6 - 1;
                bf16x8 z = (bf16x8){0,0,0,0,0,0,0,0};
                if (!edge || (row >= 0 && row < 512 && xl >= 0 && xl < 512))
                    z = *(const bf16x8*)&A[nbase + ((size_t)(row * 512 + xl)) * 64 + kb * 32 + k0];
                ar[r6] = z;
            }
#pragma unroll
            for (int ky = 0; ky < 3; ky++) {
                bf16x8 wf = *(const bf16x8*)&Wp[((kb * 9 + ky * 3 + kx) * 16 + lm) * 32 + k0];
#pragma unroll
                for (int m = 0; m < 4; m++)
                    acc[m] = __builtin_amdgcn_mfma_f32_16x16x32_bf16(ar[m + ky], wf, acc[m], 0, 0, 0);
            }
        }
    }

    if (lm < 3) {
        float bv = bias[lm];
#pragma unroll
        for (int m = 0; m < 4; m++) {
            int y = ry + m;
            int x = x0 + kg * 4;
            float4 o;
            o.x = fmaxf(acc[m][0] + bv, 0.f);
            o.y = fmaxf(acc[m][1] + bv, 0.f);
            o.z = fmaxf(acc[m][2] + bv, 0.f);
            o.w = fmaxf(acc[m][3] + bv, 0.f);
            *(float4*)&out[(((size_t)n * 3 + lm) * 512 + y) * 512 + x] = o;
        }
    }
}

// ---------------------------------------------------------------------------
// Small-map MFMA gconv (r8-proven, used for encoder/decoder stages)
// ---------------------------------------------------------------------------
template<int OCB, int NKB, int ACT, int OUTMODE>
__global__ __launch_bounds__(256, 3) void gconv_k(
    const ushort* __restrict__ s0, int n0,
    const ushort* __restrict__ s1, int n1,
    const ushort* __restrict__ Wp, const float* __restrict__ bias,
    void* __restrict__ outp, int H, int W)
{
    constexpr int NB = OCB / 16;
    const int n  = blockIdx.z;
    const int x0 = blockIdx.x * 16, y0 = blockIdx.y * 8;
    const int tid = threadIdx.x;
    const int wid = tid >> 6, lane = tid & 63;
    const int lm = lane & 15, kg = lane >> 4, k0 = kg * 8;
    const bool edge = (x0 == 0) || (x0 + 16 >= W) || (y0 == 0) || (y0 + 8 >= H);
    const int ntot = n0 + n1;
    const size_t HW = (size_t)H * W;

    const ushort* bptr[NKB];
    int bstr[NKB];
    bool bpad[NKB];
#pragma unroll
    for (int kb = 0; kb < NKB; kb++) {
        int gch = kb * 32 + k0;
        if (gch < n0)        { bptr[kb] = s0 + HW * (size_t)(n * n0) + gch;        bstr[kb] = n0; bpad[kb] = false; }
        else if (gch < ntot) { bptr[kb] = s1 + HW * (size_t)(n * n1) + (gch - n0); bstr[kb] = n1; bpad[kb] = false; }
        else                 { bptr[kb] = s0; bstr[kb] = 0; bpad[kb] = true; }
    }

    f32x4 acc[2][NB];
#pragma unroll
    for (int a = 0; a < 2; a++)
#pragma unroll
        for (int b = 0; b < NB; b++) acc[a][b] = (f32x4){0.f, 0.f, 0.f, 0.f};

#pragma unroll
    for (int kb = 0; kb < NKB; kb++) {
        bf16x8 areg[2][9];
#pragma unroll
        for (int ky = 0; ky < 3; ky++)
#pragma unroll
        for (int kx = 0; kx < 3; kx++) {
            const int t = ky * 3 + kx;
#pragma unroll
            for (int mt = 0; mt < 2; mt++) {
                int row = y0 + 2 * wid + mt + ky - 1;
                int xl  = x0 + lm + kx - 1;
                bf16x8 z = (bf16x8){0,0,0,0,0,0,0,0};
                if (!bpad[kb] && (!edge || (row >= 0 && row < H && xl >= 0 && xl < W)))
                    z = *(const bf16x8*)&bptr[kb][((size_t)(row * W + xl)) * bstr[kb]];
                areg[mt][t] = z;
            }
        }
#pragma unroll
        for (int t = 0; t < 9; t++) {
            bf16x8 wf[NB];
#pragma unroll
            for (int nb = 0; nb < NB; nb++)
                wf[nb] = *(const bf16x8*)&Wp[(((kb * 9) + t) * OCB + nb * 16 + lm) * 32 + k0];
#pragma unroll
            for (int nb = 0; nb < NB; nb++) {
#pragma unroll
                for (int mt = 0; mt < 2; mt++)
                    acc[mt][nb] = __builtin_amdgcn_mfma_f32_16x16x32_bf16(areg[mt][t], wf[nb], acc[mt][nb], 0, 0, 0);
            }
        }
    }

    if constexpr (OUTMODE == 0) {
        float* outf = (float*)outp;
#pragma unroll
        for (int mt = 0; mt < 2; mt++) {
            int y = y0 + 2 * wid + mt;
            int x = x0 + kg * 4;
#pragma unroll
            for (int nb = 0; nb < NB; nb++) {
                int oc = nb * 16 + lm;
                float bv = bias[oc];
                float r0 = acc[mt][nb][0] + bv, r1 = acc[mt][nb][1] + bv;
                float r2 = acc[mt][nb][2] + bv, r3 = acc[mt][nb][3] + bv;
                if (ACT == 1) { r0=fmaxf(r0,0.f); r1=fmaxf(r1,0.f); r2=fmaxf(r2,0.f); r3=fmaxf(r3,0.f); }
                if (ACT == 2) { r0=fast_tanh(r0); r1=fast_tanh(r1); r2=fast_tanh(r2); r3=fast_tanh(r3); }
                float4 o; o.x=r0; o.y=r1; o.z=r2; o.w=r3;
                *(float4*)&outf[(((size_t)n * OCB + oc) * H + y) * W + x] = o;
            }
        }
    } else {
        ushort* outb = (ushort*)outp;
        __shared__ ushort Ls[8 * 16 * OCB];
#pragma unroll
        for (int mt = 0; mt < 2; mt++) {
            int yy = 2 * wid + mt;
#pragma unroll
            for (int nb = 0; nb < NB; nb++) {
                int oc = nb * 16 + lm;
                float bv = bias[oc];
#pragma unroll
                for (int r = 0; r < 4; r++) {
                    float v = acc[mt][nb][r] + bv;
                    if (ACT == 1) v = fmaxf(v, 0.f);
                    if (ACT == 2) v = fast_tanh(v);
                    Ls[(yy * 16 + kg * 4 + r) * OCB + oc] = f2bf(v);
                }
            }
        }
        __syncthreads();
#pragma unroll
        for (int q = 0; q < NB; q++) {
            int off = tid * (NB * 8) + q * 8;
            int p = off / OCB, wv = off % OCB;
            int yy = p >> 4, xx = p & 15;
            *(bf16x8*)&outb[((size_t)((n * H + y0 + yy)) * W + x0 + xx) * OCB + wv] =
                *(const bf16x8*)&Ls[off];
        }
    }
}

// ---------------------------------------------------------------------------
// NHWC bf16 2x2 maxpool. C8 = channels/8. Output dims Ho x Wo.
// ---------------------------------------------------------------------------
__global__ __launch_bounds__(256) void pool_nhwc_k(
    const ushort* __restrict__ in, ushort* __restrict__ out, int C8, int Ho, int Wo)
{
    int idx = blockIdx.x * 256 + threadIdx.x;
    int total = 2 * Ho * Wo * C8;
    if (idx >= total) return;
    int s = idx % C8; int pix = idx / C8;
    int x = pix % Wo; int t = pix / Wo; int y = t % Ho; int n = t / Ho;
    int C = C8 * 8;
    const ushort* p = in + ((size_t)((n * 2 * Ho + 2 * y) * (2 * Wo) + 2 * x)) * C + s * 8;
    bf16x8 a = *(const bf16x8*)p;
    bf16x8 b = *(const bf16x8*)(p + C);
    bf16x8 c = *(const bf16x8*)(p + (size_t)(2 * Wo) * C);
    bf16x8 d = *(const bf16x8*)(p + (size_t)(2 * Wo) * C + C);
    ushort r[8];
#pragma unroll
    for (int j = 0; j < 8; j++) {
        float m = fmaxf(fmaxf(bf2f((ushort)a[j]), bf2f((ushort)b[j])),
                        fmaxf(bf2f((ushort)c[j]), bf2f((ushort)d[j])));
        r[j] = f2bf(m);
    }
    *(bf16x8*)&out[(size_t)pix * C + s * 8] = *(bf16x8*)r;
}

// ---------------------------------------------------------------------------
// NHWC bf16 bilinear up x2 (half-pixel + clamp). Input Hi x Wi.
// ---------------------------------------------------------------------------
__global__ __launch_bounds__(256) void up_nhwc_k(
    const ushort* __restrict__ in, ushort* __restrict__ out, int C8, int Hi, int Wi)
{
    int Ho = Hi * 2, Wo = Wi * 2;
    int idx = blockIdx.x * 256 + threadIdx.x;
    int total = 2 * Ho * Wo * C8;
    if (idx >= total) return;
    int s = idx % C8; int pix = idx / C8;
    int x = pix % Wo; int t = pix / Wo; int y = t % Ho; int n = t / Ho;
    int C = C8 * 8;
    float sx = (x + 0.5f) * 0.5f - 0.5f;
    float sy = (y + 0.5f) * 0.5f - 0.5f;
    int ix0 = (int)floorf(sx), iy0 = (int)floorf(sy);
    float fx = sx - ix0, fy = sy - iy0;
    int ix1 = ix0 + 1, iy1 = iy0 + 1;
    ix0 = ix0 < 0 ? 0 : ix0;           iy0 = iy0 < 0 ? 0 : iy0;
    ix1 = ix1 > Wi - 1 ? Wi - 1 : ix1; iy1 = iy1 > Hi - 1 ? Hi - 1 : iy1;
    const ushort* base = in + (size_t)n * Hi * Wi * C + s * 8;
    bf16x8 v00 = *(const bf16x8*)&base[((size_t)iy0 * Wi + ix0) * C];
    bf16x8 v01 = *(const bf16x8*)&base[((size_t)iy0 * Wi + ix1) * C];
    bf16x8 v10 = *(const bf16x8*)&base[((size_t)iy1 * Wi + ix0) * C];
    bf16x8 v11 = *(const bf16x8*)&base[((size_t)iy1 * Wi + ix1) * C];
    ushort r[8];
#pragma unroll
    for (int j = 0; j < 8; j++) {
        float a = bf2f((ushort)v00[j]), b = bf2f((ushort)v01[j]);
        float c = bf2f((ushort)v10[j]), d = bf2f((ushort)v11[j]);
        float top = a + fx * (b - a);
        float bot = c + fx * (d - c);
        r[j] = f2bf(top + fy * (bot - top));
    }
    *(bf16x8*)&out[(size_t)pix * C + s * 8] = *(bf16x8*)r;
}

// ---------------------------------------------------------------------------
// NCHW fp32 16ch -> NHWC16 bf16
// ---------------------------------------------------------------------------
__global__ __launch_bounds__(256) void cvt16_k(
    const float* __restrict__ src, ushort* __restrict__ dst)
{
    int idx = blockIdx.x * 256 + threadIdx.x;
    int x = idx & 511, y = (idx >> 9) & 511, n = idx >> 18;
    const float* base = src + (size_t)n * 16 * 262144 + y * 512 + x;
    ushort vals[16];
#pragma unroll
    for (int c = 0; c < 16; c++) vals[c] = f2bf(base[(size_t)c * 262144]);
    ushort* d = dst + (size_t)idx * 16;
    *(bf16x8*)(d)     = *(bf16x8*)(vals);
    *(bf16x8*)(d + 8) = *(bf16x8*)(vals + 8);
}

// ---------------------------------------------------------------------------
// Direct VALU conv (fp32 in). OUTW 0: fp32 NCHW out; 1: bf16 NHWC16 out.
// ---------------------------------------------------------------------------
template<int K, int OCB, int ACT, int PIX, int OUTW>
__global__ __launch_bounds__(256, 3) void conv_k(
    const float* __restrict__ src0, int c0,
    const float* __restrict__ src1, int c1,
    const float* __restrict__ src2, int c2,
    const float* __restrict__ src3, int c3,
    const float* __restrict__ w, const float* __restrict__ bias,
    void* __restrict__ outp, int H, int W, int OC, int ocChunks)
{
    constexpr int TW = 32, TH = 8 * PIX, P = K / 2;
    constexpr int TLW = TW + K - 1, TLH = TH + K - 1;
    constexpr int TLWP = (K == 3) ? 36 : 40;
    constexpr int CB = 4;
    __shared__ float tile[CB][TLH][TLWP];

    const int z   = blockIdx.z;
    const int n   = z / ocChunks;
    const int ocb = (z - n * ocChunks) * OCB;
    const int tx  = threadIdx.x & 31;
    const int ty  = threadIdx.x >> 5;
    const int x0  = blockIdx.x * TW, y0 = blockIdx.y * TH;
    const int Cin = c0 + c1 + c2 + c3;

    float acc[OCB][PIX];
#pragma unroll
    for (int i = 0; i < OCB; i++)
#pragma unroll
        for (int p = 0; p < PIX; p++) acc[i][p] = 0.f;

    int cgbase = 0;
#pragma unroll
    for (int s = 0; s < 4; s++) {
        const float* sp = (s == 0) ? src0 : (s == 1) ? src1 : (s == 2) ? src2 : src3;
        const int    cn = (s == 0) ? c0   : (s == 1) ? c1   : (s == 2) ? c2   : c3;
        for (int cb = 0; cb < cn; cb += CB) {
            const int nch = (cn - cb < CB) ? (cn - cb) : CB;
            __syncthreads();
            for (int idx = threadIdx.x; idx < nch * TLH * TLW; idx += 256) {
                int ch = idx / (TLH * TLW); int rem = idx - ch * (TLH * TLW);
                int r = rem / TLW, cc = rem - r * TLW;
                int gy = y0 + r - P, gx = x0 + cc - P;
                float vv = 0.f;
                if (gy >= 0 && gy < H && gx >= 0 && gx < W)
                    vv = sp[(size_t)(n * cn + cb + ch) * H * W + (size_t)gy * W + gx];
                tile[ch][r][cc] = vv;
            }
            __syncthreads();
            for (int c = 0; c < nch; c++) {
                float v[PIX + K - 1][K];
#pragma unroll
                for (int r = 0; r < PIX + K - 1; r++)
#pragma unroll
                    for (int cc = 0; cc < K; cc++)
                        v[r][cc] = tile[c][ty * PIX + r][tx + cc];
                const float* wc = w + ((size_t)ocb * Cin + (cgbase + cb + c)) * (K * K);
#pragma unroll
                for (int oc = 0; oc < OCB; oc++) {
                    const float* wo = wc + (size_t)oc * Cin * (K * K);
#pragma unroll
                    for (int ky = 0; ky < K; ky++)
#pragma unroll
                        for (int kx = 0; kx < K; kx++) {
                            float ww = wo[ky * K + kx];
#pragma unroll
                            for (int p = 0; p < PIX; p++)
                                acc[oc][p] = fmaf(ww, v[ky + p][kx], acc[oc][p]);
                        }
                }
            }
        }
        cgbase += cn;
    }

    const int xx = x0 + tx, yy = y0 + ty * PIX;
    if constexpr (OUTW == 0) {
        float* out = (float*)outp;
#pragma unroll
        for (int oc = 0; oc < OCB; oc++) {
            int o = ocb + oc;
            float b = bias[o];
#pragma unroll
            for (int p = 0; p < PIX; p++) {
                float r = acc[oc][p] + b;
                if (ACT == 1) r = fmaxf(r, 0.f);
                if (ACT == 2) r = tanhf(r);
                out[(((size_t)n * OC + o) * H + (yy + p)) * W + xx] = r;
            }
        }
    } else {
        ushort* ob = (ushort*)outp;
#pragma unroll
        for (int p = 0; p < PIX; p++) {
            ushort v16[16];
#pragma unroll
            for (int oc = 0; oc < OCB; oc++) {
                float r = acc[oc][p] + bias[oc];
                if (ACT == 1) r = fmaxf(r, 0.f);
                if (ACT == 2) r = tanhf(r);
                v16[oc] = f2bf(r);
            }
            ushort* d = &ob[(((size_t)n * H + (yy + p)) * W + xx) * 16];
            *(bf16x8*)d       = *(bf16x8*)v16;
            *(bf16x8*)(d + 8) = *(bf16x8*)(v16 + 8);
        }
    }
}

// ---------------------------------------------------------------------------
__global__ __launch_bounds__(256) void pool_k(
    const float* __restrict__ in, float* __restrict__ out, int NC, int H, int W)
{
    int H2 = H >> 1, W2 = W >> 1;
    int total = NC * H2 * W2;
    int idx = blockIdx.x * 256 + threadIdx.x;
    if (idx >= total) return;
    int x = idx % W2; int t = idx / W2; int y = t % H2; int q = t / H2;
    const float* p = in + ((size_t)q * H + 2 * y) * W + 2 * x;
    out[idx] = fmaxf(fmaxf(p[0], p[1]), fmaxf(p[W], p[W + 1]));
}

// ---------------------------------------------------------------------------
__global__ __launch_bounds__(256) void up_k(
    const float* __restrict__ in, float* __restrict__ out, int NC, int Hi, int Wi, int s)
{
    int Ho = Hi * s, Wo = Wi * s;
    int total = NC * Ho * Wo;
    int idx = blockIdx.x * 256 + threadIdx.x;
    if (idx >= total) return;
    int x = idx % Wo; int t = idx / Wo; int y = t % Ho; int q = t / Ho;
    float inv = 1.0f / (float)s;
    float sx = (x + 0.5f) * inv - 0.5f;
    float sy = (y + 0.5f) * inv - 0.5f;
    int ix0 = (int)floorf(sx), iy0 = (int)floorf(sy);
    float fx = sx - ix0, fy = sy - iy0;
    int ix1 = ix0 + 1, iy1 = iy0 + 1;
    ix0 = ix0 < 0 ? 0 : ix0;           iy0 = iy0 < 0 ? 0 : iy0;
    ix1 = ix1 > Wi - 1 ? Wi - 1 : ix1; iy1 = iy1 > Hi - 1 ? Hi - 1 : iy1;
    const float* p = in + (size_t)q * Hi * Wi;
    float v00 = p[(size_t)iy0 * Wi + ix0], v01 = p[(size_t)iy0 * Wi + ix1];
    float v10 = p[(size_t)iy1 * Wi + ix0], v11 = p[(size_t)iy1 * Wi + ix1];
    float top = v00 + fx * (v01 - v00);
    float bot = v10 + fx * (v11 - v10);
    out[idx] = top + fy * (bot - top);
}

// ---------------------------------------------------------------------------
__device__ __forceinline__ void scan_pair(const float a[8], float x1[8], float x2[8], int lane)
{
    float P = 1.f, Q1 = 0.f, Q2 = 0.f;
#pragma unroll
    for (int j = 0; j < 8; j++) {
        float av = a[j];
        Q1 = fmaf(av, Q1, (1.f - av) * x1[j]);
        Q2 = fmaf(av, Q2, (1.f - av) * x2[j]);
        P *= av;
    }
#pragma unroll
    for (int d = 1; d < 64; d <<= 1) {
        float Pp  = __shfl_up(P,  (unsigned)d);
        float Q1p = __shfl_up(Q1, (unsigned)d);
        float Q2p = __shfl_up(Q2, (unsigned)d);
        if (lane >= d) {
            Q1 = fmaf(P, Q1p, Q1);
            Q2 = fmaf(P, Q2p, Q2);
            P *= Pp;
        }
    }
    float h1in = __shfl_up(Q1, 1u);
    float h2in = __shfl_up(Q2, 1u);
    if (lane == 0) { h1in = 0.f; h2in = 0.f; }
    float s1 = h1in, s2 = h2in;
#pragma unroll
    for (int j = 0; j < 8; j++) {
        float av = a[j];
        s1 = fmaf(av, s1, (1.f - av) * x1[j]);
        s2 = fmaf(av, s2, (1.f - av) * x2[j]);
        x1[j] = s1; x2[j] = s2;
    }
}

__global__ __launch_bounds__(256) void scan_h_fused(
    const float* __restrict__ c9, const float* __restrict__ ms,
    float* __restrict__ hm)
{
    int gw   = (blockIdx.x * 256 + threadIdx.x) >> 6;
    int lane = threadIdx.x & 63;
    int y = gw & 511; int nc = gw >> 9; int c = nc & 15; int n = nc >> 4;
    const float* a1row = c9 + ((((size_t)n * 64 + c)      * 512 + y) << 9);
    const float* a2row = c9 + ((((size_t)n * 64 + 32 + c) * 512 + y) << 9);
    const size_t rowoff = (size_t)gw << 9;
    const float* ur = ms + rowoff;
    int t0 = lane << 3;

    float a1[8], a2[8], x1[8], x2[8];
    {
        float4 b0 = *(const float4*)(a1row + t0);
        float4 b1 = *(const float4*)(a1row + t0 + 4);
        a1[0]=b0.x; a1[1]=b0.y; a1[2]=b0.z; a1[3]=b0.w;
        a1[4]=b1.x; a1[5]=b1.y; a1[6]=b1.z; a1[7]=b1.w;
    }
    {
        float4 b0 = *(const float4*)(a2row + t0);
        float4 b1 = *(const float4*)(a2row + t0 + 4);
        a2[0]=b0.x; a2[1]=b0.y; a2[2]=b0.z; a2[3]=b0.w;
        a2[4]=b1.x; a2[5]=b1.y; a2[6]=b1.z; a2[7]=b1.w;
    }
    {
        float4 b0 = *(const float4*)(ur + t0);
        float4 b1 = *(const float4*)(ur + t0 + 4);
        x1[0]=b0.x; x1[1]=b0.y; x1[2]=b0.z; x1[3]=b0.w;
        x1[4]=b1.x; x1[5]=b1.y; x1[6]=b1.z; x1[7]=b1.w;
    }
    {
        float4 r0 = *(const float4*)(ur + (508 - t0));
        float4 r1 = *(const float4*)(ur + (504 - t0));
        x2[0]=r0.w; x2[1]=r0.z; x2[2]=r0.y; x2[3]=r0.x;
        x2[4]=r1.w; x2[5]=r1.z; x2[6]=r1.y; x2[7]=r1.x;
    }

    scan_pair(a1, x1, x2, lane);

    float r[8];
#pragma unroll
    for (int j = 0; j < 8; j++) r[j] = __shfl(x2[7 - j], 63 - lane);

    scan_pair(a2, x1, r, lane);

    float w0[4], w1[4];
#pragma unroll
    for (int j = 0; j < 4; j++) { w0[j] = fmaxf(x1[j], r[j]); w1[j] = fmaxf(x1[j+4], r[j+4]); }
    *(float4*)(hm + rowoff + t0)     = make_float4(w0[0], w0[1], w0[2], w0[3]);
    *(float4*)(hm + rowoff + t0 + 4) = make_float4(w1[0], w1[1], w1[2], w1[3]);
}

// ---------------------------------------------------------------------------
#define SV_DECODE \
    int g = blockIdx.x * 256 + threadIdx.x; \
    int x = g & 511; int nc = (g >> 9) & 31; int seg = g >> 14; \
    int c = nc & 15; int n = nc >> 4; int ys = seg << 6; (void)c; (void)n;

__global__ __launch_bounds__(256) void sv_a(
    const float* __restrict__ c9, const float* __restrict__ ms, float* __restrict__ SB)
{
    SV_DECODE
    const float* gx1 = c9 + (((size_t)n * 64 + c)      << 18) + x;
    const float* gy1 = c9 + (((size_t)n * 64 + 16 + c) << 18) + x;
    const float* u   = ms + ((size_t)nc << 18) + x;
    float P = 1.f, Q3 = 0.f, Q4 = 0.f;
    for (int i = 0; i < 64; i++) {
        int y = ys + i;
        float g3 = (y == 0) ? gy1[0] : gx1[(size_t)y << 9];
        float uf = u[(size_t)y << 9];
        float ub = u[(size_t)(511 - y) << 9];
        Q3 = fmaf(g3, Q3, (1.f - g3) * uf);
        Q4 = fmaf(g3, Q4, (1.f - g3) * ub);
        P *= g3;
    }
    SB[g] = P; SB[131072 + g] = Q3; SB[262144 + g] = Q4;
}

__global__ __launch_bounds__(256) void sv_b(
    float* __restrict__ c9, const float* __restrict__ ms,
    float* __restrict__ SB, float* __restrict__ h3buf)
{
    SV_DECODE
    const float* gx1 = c9 + (((size_t)n * 64 + c)      << 18) + x;
    const float* gy1 = c9 + (((size_t)n * 64 + 16 + c) << 18) + x;
    const float* gy2 = c9 + (((size_t)n * 64 + 48 + c) << 18) + x;
    float*       h4p = c9 + (((size_t)n * 64 + 32 + c) << 18) + x;
    const float* u   = ms + ((size_t)nc << 18) + x;
    float*       h3p = h3buf + ((size_t)nc << 18) + x;
    int gc = g & 16383;
    float s3 = 0.f, s4 = 0.f;
    for (int j = 0; j < seg; j++) {
        float Pj  = SB[j * 16384 + gc];
        float Q3j = SB[131072 + j * 16384 + gc];
        float Q4j = SB[262144 + j * 16384 + gc];
        s3 = fmaf(Pj, s3, Q3j);
        s4 = fmaf(Pj, s4, Q4j);
    }
    float P7 = 1.f, Q7 = 0.f;
    for (int i = 0; i < 64; i++) {
        int y = ys + i;
        float g3 = (y == 0) ? gy1[0] : gx1[(size_t)y << 9];
        float uf = u[(size_t)y << 9];
        float ub = u[(size_t)(511 - y) << 9];
        s3 = fmaf(g3, s3, (1.f - g3) * uf);
        s4 = fmaf(g3, s4, (1.f - g3) * ub);
        h3p[(size_t)y << 9] = s3;
        h4p[(size_t)y << 9] = s4;
        float g7 = gy2[(size_t)y << 9];
        Q7 = fmaf(g7, Q7, (1.f - g7) * s3);
        P7 *= g7;
    }
    SB[393216 + g] = P7; SB[524288 + g] = Q7;
}

__global__ __launch_bounds__(256) void sv_c(
    const float* __restrict__ c9, const float* __restrict__ h3buf,
    float* __restrict__ SB, float* __restrict__ hm)
{
    SV_DECODE
    const float* gy2 = c9 + (((size_t)n * 64 + 48 + c) << 18) + x;
    const float* h4p = c9 + (((size_t)n * 64 + 32 + c) << 18) + x;
    const float* h3p = h3buf + ((size_t)nc << 18) + x;
    float*       o   = hm + ((size_t)nc << 18) + x;
    int gc = g & 16383;
    float s7 = 0.f;
    for (int j = 0; j < seg; j++) {
        float Pj = SB[393216 + j * 16384 + gc];
        float Qj = SB[524288 + j * 16384 + gc];
        s7 = fmaf(Pj, s7, Qj);
    }
    float P8 = 1.f, Q8 = 0.f;
    for (int i = 0; i < 64; i++) {
        int y = ys + i;
        float g7 = gy2[(size_t)y << 9];
        float hv = h3p[(size_t)y << 9];
        s7 = fmaf(g7, s7, (1.f - g7) * hv);
        o[(size_t)y << 9] = fmaxf(o[(size_t)y << 9], s7);
        float u8 = h4p[(size_t)(511 - y) << 9];
        Q8 = fmaf(g7, Q8, (1.f - g7) * u8);
        P8 *= g7;
    }
    SB[655360 + g] = P8; SB[786432 + g] = Q8;
}

__global__ __launch_bounds__(256) void sv_d(
    const float* __restrict__ c9, const float* __restrict__ SB, float* __restrict__ hm)
{
    SV_DECODE
    const float* gy2 = c9 + (((size_t)n * 64 + 48 + c) << 18) + x;
    const float* h4p = c9 + (((size_t)n * 64 + 32 + c) << 18) + x;
    float*       o   = hm + ((size_t)nc << 18) + x;
    int gc = g & 16383;
    float s8 = 0.f;
    for (int j = 0; j < seg; j++) {
        float Pj = SB[655360 + j * 16384 + gc];
        float Qj = SB[786432 + j * 16384 + gc];
        s8 = fmaf(Pj, s8, Qj);
    }
    for (int i = 0; i < 64; i++) {
        int y = ys + i;
        float g7 = gy2[(size_t)y << 9];
        float u8 = h4p[(size_t)(511 - y) << 9];
        s8 = fmaf(g7, s8, (1.f - g7) * u8);
        o[(size_t)y << 9] = fmaxf(o[(size_t)y << 9], s8);
    }
}

// ---------------------------------------------------------------------------
extern "C" void kernel_launch(void* const* d_in, const int* in_sizes, int n_in,
                              void* d_out, int out_size, void* d_ws, size_t ws_size,
                              hipStream_t stream)
{
    const float* x    = (const float*)d_in[0];
    const float* w_s1 = (const float*)d_in[1];  const float* b_s1 = (const float*)d_in[2];
    const float* w_mc = (const float*)d_in[3];  const float* b_mc = (const float*)d_in[4];
    const float* w2   = (const float*)d_in[5];  const float* b2   = (const float*)d_in[6];
    const float* w3   = (const float*)d_in[7];  const float* b3   = (const float*)d_in[8];
    const float* w4   = (const float*)d_in[9];  const float* b4   = (const float*)d_in[10];
    const float* w5   = (const float*)d_in[11]; const float* b5   = (const float*)d_in[12];
    const float* w6   = (const float*)d_in[13]; const float* b6   = (const float*)d_in[14];
    const float* w6s  = (const float*)d_in[15]; const float* b6s  = (const float*)d_in[16];
    const float* w7   = (const float*)d_in[17]; const float* b7   = (const float*)d_in[18];
    const float* w8   = (const float*)d_in[19]; const float* b8   = (const float*)d_in[20];
    const float* w9   = (const float*)d_in[21]; const float* b9   = (const float*)d_in[22];
    const float* w10  = (const float*)d_in[23]; const float* b10  = (const float*)d_in[24];
    const float* w11  = (const float*)d_in[25]; const float* b11  = (const float*)d_in[26];
    float* out = (float*)d_out;
    float* ws  = (float*)d_ws;

    const size_t NEEDED = 60817408ull * 4ull;   // 232 MiB (verified r2-r9)
    if (ws_size < NEEDED) return;

    // -------- global regions (floats from ws) --------
    float* MS    = ws;                 // [2,16,512,512] fp32 (scan u)
    float* C9    = ws + 8388608;       // [2,64,512,512] fp32 gates (+h4) -> A11
    float* H3REG = ws + 41943040;      // u2/u3/u4 (phase A) -> h3 (scans) -> A10
    float* AR    = ws + 50331648;      // arena, 10,485,760 floats

    // packed weights (permanent, arena head)
    ushort* WREG = (ushort*)AR;
    ushort* wp3  = WREG + 0;      ushort* wp4  = WREG + 9216;
    ushort* wp5  = WREG + 18432;  ushort* wp6  = WREG + 27648;
    ushort* wp6s = WREG + 46080;  ushort* wp7  = WREG + 82944;
    ushort* wp8  = WREG + 110592; ushort* wp9  = WREG + 119808;
    ushort* wp10 = WREG + 138240; ushort* wp11 = WREG + 156672;

    // phase A (fp32 multi-scale)
    ushort* C2b = (ushort*)(AR + 163840);   // [2,512,512,16] bf16, live -> gconv9
    float* s1f = AR + 4358144;
    float* s2f = AR + 5931008;
    float* s3f = AR + 6324224;
    float* s4f = AR + 6422528;
    float* u2  = H3REG + 0;
    float* u3  = H3REG + 1572864;
    float* u4  = H3REG + 3145728;
    // phase B (NHWC bf16 encoder/decoder, liveness-packed)
    ushort* p2    = (ushort*)(AR + 4358144);
    ushort* c3    = (ushort*)(AR + 5406720);
    ushort* p3    = (ushort*)(AR + 7503872);
    ushort* c4    = (ushort*)(AR + 8028160);
    ushort* p4    = (ushort*)(AR + 8552448);
    ushort* c5    = (ushort*)(AR + 8683520);
    ushort* p5    = (ushort*)(AR + 8814592);
    ushort* c6    = (ushort*)(AR + 8847360);
    ushort* u6    = (ushort*)(AR + 8912896);
    ushort* t6    = (ushort*)(AR + 9175040);
    ushort* c6re  = (ushort*)(AR + 9437184);
    ushort* c7pre = (ushort*)(AR + 7503872);  // p3 slot
    ushort* c7    = (ushort*)(AR + 8028160);  // c4..c6re slots
    ushort* c8pre = (ushort*)(AR + 4358144);  // p2 slot
    ushort* c8b   = (ushort*)(AR + 5406720);  // c3..c7 slots
    // scans / head
    float* SB  = AR + 163840;
    float* HM  = AR + 1081344;
    float* H3  = H3REG;
    ushort* A10 = (ushort*)H3REG;
    ushort* A11 = (ushort*)C9;

    auto cdiv = [](int a, int b) { return (a + b - 1) / b; };

    // ---- pack all weights (inputs are constant) ----
    packw_k<<<36,256,0,stream>>>(w3,  wp3,  32, 32, 16, 1);
    packw_k<<<36,256,0,stream>>>(w4,  wp4,  32, 32, 32, 1);
    packw_k<<<36,256,0,stream>>>(w5,  wp5,  32, 32, 32, 1);
    packw_k<<<72,256,0,stream>>>(w6,  wp6,  64, 64, 32, 1);
    packw_k<<<144,256,0,stream>>>(w6s, wp6s, 64, 64, 64, 2);
    packw_k<<<108,256,0,stream>>>(w7,  wp7,  32, 32, 96, 3);
    packw_k<<<36,256,0,stream>>>(w8,  wp8,  16, 16, 64, 2);
    packw_k<<<72,256,0,stream>>>(w9,  wp9,  64, 64, 32, 1);
    packw_k<<<72,256,0,stream>>>(w10, wp10, 64, 64, 16, 1);
    packw_k<<<36,256,0,stream>>>(w11, wp11, 16, 3,  64, 2);

    // ---- phase A: w2 (bf16 NHWC out) + multi-scale (fp32) ----
    conv_k<5,16,1,2,1><<<dim3(16,32,2),256,0,stream>>>(x,3,nullptr,0,nullptr,0,nullptr,0,
                                                       w2,b2, C2b, 512,512,16,1);
    conv_k<3,3,0,2,0><<<dim3(16,32,2),256,0,stream>>>(x,3,nullptr,0,nullptr,0,nullptr,0,
                                                      w_s1,b_s1, s1f, 512,512,3,1);
    pool_k<<<cdiv(2*3*256*256,256),256,0,stream>>>(s1f, s2f, 6, 512, 512);
    pool_k<<<cdiv(2*3*128*128,256),256,0,stream>>>(s2f, s3f, 6, 256, 256);
    pool_k<<<cdiv(2*3*64*64,  256),256,0,stream>>>(s3f, s4f, 6, 128, 128);
    up_k<<<6144,256,0,stream>>>(s2f, u2, 6, 256, 256, 2);
    up_k<<<6144,256,0,stream>>>(s3f, u3, 6, 128, 128, 4);
    up_k<<<6144,256,0,stream>>>(s4f, u4, 6, 64, 64, 8);
    conv_k<3,16,0,2,0><<<dim3(16,32,2),256,0,stream>>>(s1f,3,u2,3,u3,3,u4,3,
                                                       w_mc,b_mc, MS, 512,512,16,1);

    // ---- encoder / decoder (NHWC bf16, MFMA) ----
    pool_nhwc_k<<<1024,256,0,stream>>>(C2b, p2, 2, 256, 256);
    gconv_k<32,1,1,1><<<dim3(16,32,2),256,0,stream>>>(p2,16,nullptr,0, wp3,b3, c3, 256,256);
    pool_nhwc_k<<<512,256,0,stream>>>(c3, p3, 4, 128, 128);
    gconv_k<32,1,1,1><<<dim3(8,16,2),256,0,stream>>>(p3,32,nullptr,0, wp4,b4, c4, 128,128);
    pool_nhwc_k<<<128,256,0,stream>>>(c4, p4, 4, 64, 64);
    gconv_k<32,1,1,1><<<dim3(4,8,2),256,0,stream>>>(p4,32,nullptr,0, wp5,b5, c5, 64,64);
    pool_nhwc_k<<<32,256,0,stream>>>(c5, p5, 4, 32, 32);
    gconv_k<64,1,1,1><<<dim3(2,4,2),256,0,stream>>>(p5,32,nullptr,0, wp6,b6, c6, 32,32);
    up_nhwc_k<<<256,256,0,stream>>>(c6, u6, 8, 32, 32);
    gconv_k<64,2,1,1><<<dim3(4,8,2),256,0,stream>>>(u6,64,nullptr,0, wp6s,b6s, t6, 64,64);
    up_nhwc_k<<<1024,256,0,stream>>>(t6, c6re, 8, 64, 64);
    gconv_k<32,3,1,1><<<dim3(8,16,2),256,0,stream>>>(c6re,64, c4,32, wp7,b7, c7pre, 128,128);
    up_nhwc_k<<<2048,256,0,stream>>>(c7pre, c7, 4, 128, 128);
    gconv_k<16,2,1,1><<<dim3(16,32,2),256,0,stream>>>(c7,32, c3,32, wp8,b8, c8pre, 256,256);
    up_nhwc_k<<<4096,256,0,stream>>>(c8pre, c8b, 2, 256, 256);
    gconv_mr<64,1,2,0><<<dim3(32,32,2),256,0,stream>>>(c8b,16, C2b,16, wp9,b9, C9, 512,512);

    // ---- linear recurrence scans (fp32, proven) ----
    scan_h_fused<<<4096,256,0,stream>>>(C9, MS, HM);
    sv_a<<<512,256,0,stream>>>(C9, MS, SB);
    sv_b<<<512,256,0,stream>>>(C9, MS, SB, H3);
    sv_c<<<512,256,0,stream>>>(C9, H3, SB, HM);
    sv_d<<<512,256,0,stream>>>(C9, SB, HM);

    // ---- head: c10 + w11 (MFMA, multi-row) ----
    cvt16_k<<<2048,256,0,stream>>>(HM, A10);
    gconv_mr<64,1,1,1><<<dim3(32,32,2),256,0,stream>>>(A10,16,nullptr,0, wp10,b10, A11, 512,512);
    gconv11_mr<<<dim3(32,32,2),256,0,stream>>>(A11, wp11, b11, out);
    (void)in_sizes; (void)n_in; (void)out_size; (void)ws_size;
}

// Round 12
// 579.061 us; speedup vs baseline: 1.2068x; 1.2068x over previous
//
#include <hip/hip_runtime.h>
#include <math.h>

typedef float  f32x4  __attribute__((ext_vector_type(4)));
typedef short  bf16x8 __attribute__((ext_vector_type(8)));

__device__ __forceinline__ ushort f2bf(float f) {
    unsigned u = __float_as_uint(f);
    unsigned r = (u + 0x7fffu + ((u >> 16) & 1u)) >> 16;
    return (ushort)r;
}
__device__ __forceinline__ float bf2f(ushort u) {
    return __uint_as_float(((unsigned)u) << 16);
}
__device__ __forceinline__ float fast_tanh(float x) {
    float e = __expf(2.f * x);
    return 1.f - 2.f / (e + 1.f);
}

// ---------------------------------------------------------------------------
// Generic weight packer: w[oc][ic][3][3] fp32 -> Wp[kb][t][ocp][32] bf16
// ---------------------------------------------------------------------------
__global__ __launch_bounds__(256) void packw_k(
    const float* __restrict__ w, ushort* __restrict__ dst,
    int OCpad, int OCreal, int Cin, int nkb)
{
    int i = blockIdx.x * 256 + threadIdx.x;
    int total = nkb * 9 * OCpad * 32;
    if (i >= total) return;
    int ic32 = i & 31;
    int oc = (i >> 5) % OCpad;
    int t  = (i / (32 * OCpad)) % 9;
    int kb = i / (32 * OCpad * 9);
    int gic = kb * 32 + ic32;
    float v = 0.f;
    if (oc < OCreal && gic < Cin) v = w[((size_t)oc * Cin + gic) * 9 + t];
    dst[i] = f2bf(v);
}

// ---------------------------------------------------------------------------
// Multi-row MFMA 3x3 conv (r10-proven). OUTMODE 0: fp32 NCHW; 1: bf16 NHWC.
// ---------------------------------------------------------------------------
template<int OCB, int NKB, int ACT, int OUTMODE>
__global__ __launch_bounds__(256, 3) void gconv_mr(
    const ushort* __restrict__ s0, int n0,
    const ushort* __restrict__ s1, int n1,
    const ushort* __restrict__ Wp, const float* __restrict__ bias,
    void* __restrict__ outp, int H, int W)
{
    constexpr int NB = OCB / 16;
    const int n  = blockIdx.z;
    const int x0 = blockIdx.x * 16, y0 = blockIdx.y * 16;
    const int tid = threadIdx.x;
    const int wid = tid >> 6, lane = tid & 63;
    const int lm = lane & 15, kg = lane >> 4, k0 = kg * 8;
    const int ry = y0 + 4 * wid;
    const bool edge = (x0 == 0) || (x0 + 16 >= W) || (ry == 0) || (ry + 4 >= H);
    const int ntot = n0 + n1;
    const size_t HW = (size_t)H * W;

    const ushort* bptr[NKB];
    int bstr[NKB];
    bool bpad[NKB];
#pragma unroll
    for (int kb = 0; kb < NKB; kb++) {
        int gch = kb * 32 + k0;
        if (gch < n0)        { bptr[kb] = s0 + HW * (size_t)(n * n0) + gch;        bstr[kb] = n0; bpad[kb] = false; }
        else if (gch < ntot) { bptr[kb] = s1 + HW * (size_t)(n * n1) + (gch - n0); bstr[kb] = n1; bpad[kb] = false; }
        else                 { bptr[kb] = s0; bstr[kb] = 0; bpad[kb] = true; }
    }

    f32x4 acc[4][NB];
#pragma unroll
    for (int m = 0; m < 4; m++)
#pragma unroll
        for (int b = 0; b < NB; b++) acc[m][b] = (f32x4){0.f, 0.f, 0.f, 0.f};

#pragma unroll
    for (int kb = 0; kb < NKB; kb++) {
#pragma unroll
        for (int kx = 0; kx < 3; kx++) {
            bf16x8 ar[6];
            const int xl = x0 + lm + kx - 1;
#pragma unroll
            for (int r6 = 0; r6 < 6; r6++) {
                int row = ry + r6 - 1;
                bf16x8 z = (bf16x8){0,0,0,0,0,0,0,0};
                if (!bpad[kb] && (!edge || (row >= 0 && row < H && xl >= 0 && xl < W)))
                    z = *(const bf16x8*)&bptr[kb][((size_t)(row * W + xl)) * bstr[kb]];
                ar[r6] = z;
            }
#pragma unroll
            for (int ky = 0; ky < 3; ky++) {
                bf16x8 wf[NB];
#pragma unroll
                for (int nb = 0; nb < NB; nb++)
                    wf[nb] = *(const bf16x8*)&Wp[(((kb * 9) + ky * 3 + kx) * OCB + nb * 16 + lm) * 32 + k0];
#pragma unroll
                for (int nb = 0; nb < NB; nb++)
#pragma unroll
                    for (int m = 0; m < 4; m++)
                        acc[m][nb] = __builtin_amdgcn_mfma_f32_16x16x32_bf16(ar[m + ky], wf[nb], acc[m][nb], 0, 0, 0);
            }
        }
    }

    if constexpr (OUTMODE == 0) {
        float* outf = (float*)outp;
#pragma unroll
        for (int m = 0; m < 4; m++) {
            int y = ry + m;
            int x = x0 + kg * 4;
#pragma unroll
            for (int nb = 0; nb < NB; nb++) {
                int oc = nb * 16 + lm;
                float bv = bias[oc];
                float r0 = acc[m][nb][0] + bv, r1 = acc[m][nb][1] + bv;
                float r2 = acc[m][nb][2] + bv, r3 = acc[m][nb][3] + bv;
                if (ACT == 1) { r0=fmaxf(r0,0.f); r1=fmaxf(r1,0.f); r2=fmaxf(r2,0.f); r3=fmaxf(r3,0.f); }
                if (ACT == 2) { r0=fast_tanh(r0); r1=fast_tanh(r1); r2=fast_tanh(r2); r3=fast_tanh(r3); }
                float4 o; o.x=r0; o.y=r1; o.z=r2; o.w=r3;
                *(float4*)&outf[(((size_t)n * OCB + oc) * H + y) * W + x] = o;
            }
        }
    } else {
        ushort* outb = (ushort*)outp;
        __shared__ ushort Ls[16 * 16 * OCB];
#pragma unroll
        for (int m = 0; m < 4; m++) {
            int yy = 4 * wid + m;
#pragma unroll
            for (int nb = 0; nb < NB; nb++) {
                int oc = nb * 16 + lm;
                float bv = bias[oc];
#pragma unroll
                for (int r = 0; r < 4; r++) {
                    float v = acc[m][nb][r] + bv;
                    if (ACT == 1) v = fmaxf(v, 0.f);
                    if (ACT == 2) v = fast_tanh(v);
                    Ls[(yy * 16 + kg * 4 + r) * OCB + oc] = f2bf(v);
                }
            }
        }
        __syncthreads();
        constexpr int NQ = OCB / 8;
#pragma unroll
        for (int q = 0; q < NQ; q++) {
            int off = q * 2048 + tid * 8;
            int p = off / OCB, wv = off % OCB;
            int yy = p >> 4, xx = p & 15;
            *(bf16x8*)&outb[((size_t)((n * H + y0 + yy)) * W + x0 + xx) * OCB + wv] =
                *(const bf16x8*)&Ls[off];
        }
    }
}

// ---------------------------------------------------------------------------
// w11 multi-row: A NHWC64 @512^2 -> out [2][3][512][512] fp32, relu.
// ---------------------------------------------------------------------------
__global__ __launch_bounds__(256, 3) void gconv11_mr(
    const ushort* __restrict__ A, const ushort* __restrict__ Wp,
    const float* __restrict__ bias, float* __restrict__ out)
{
    const int n  = blockIdx.z;
    const int x0 = blockIdx.x * 16, y0 = blockIdx.y * 16;
    const int tid = threadIdx.x;
    const int wid = tid >> 6, lane = tid & 63;
    const int lm = lane & 15, kg = lane >> 4, k0 = kg * 8;
    const int ry = y0 + 4 * wid;
    const bool edge = (x0 == 0) || (x0 + 16 >= 512) || (ry == 0) || (ry + 4 >= 512);
    const size_t nbase = (size_t)n * 262144 * 64;

    f32x4 acc[4];
#pragma unroll
    for (int m = 0; m < 4; m++) acc[m] = (f32x4){0.f,0.f,0.f,0.f};

#pragma unroll
    for (int kb = 0; kb < 2; kb++) {
#pragma unroll
        for (int kx = 0; kx < 3; kx++) {
            bf16x8 ar[6];
            const int xl = x0 + lm + kx - 1;
#pragma unroll
            for (int r6 = 0; r6 < 6; r6++) {
                int row = ry + r6 - 1;
                bf16x8 z = (bf16x8){0,0,0,0,0,0,0,0};
                if (!edge || (row >= 0 && row < 512 && xl >= 0 && xl < 512))
                    z = *(const bf16x8*)&A[nbase + ((size_t)(row * 512 + xl)) * 64 + kb * 32 + k0];
                ar[r6] = z;
            }
#pragma unroll
            for (int ky = 0; ky < 3; ky++) {
                bf16x8 wf = *(const bf16x8*)&Wp[((kb * 9 + ky * 3 + kx) * 16 + lm) * 32 + k0];
#pragma unroll
                for (int m = 0; m < 4; m++)
                    acc[m] = __builtin_amdgcn_mfma_f32_16x16x32_bf16(ar[m + ky], wf, acc[m], 0, 0, 0);
            }
        }
    }

    if (lm < 3) {
        float bv = bias[lm];
#pragma unroll
        for (int m = 0; m < 4; m++) {
            int y = ry + m;
            int x = x0 + kg * 4;
            float4 o;
            o.x = fmaxf(acc[m][0] + bv, 0.f);
            o.y = fmaxf(acc[m][1] + bv, 0.f);
            o.z = fmaxf(acc[m][2] + bv, 0.f);
            o.w = fmaxf(acc[m][3] + bv, 0.f);
            *(float4*)&out[(((size_t)n * 3 + lm) * 512 + y) * 512 + x] = o;
        }
    }
}

// ---------------------------------------------------------------------------
// Small-map MFMA gconv (r8-proven, encoder/decoder stages)
// ---------------------------------------------------------------------------
template<int OCB, int NKB, int ACT, int OUTMODE>
__global__ __launch_bounds__(256, 3) void gconv_k(
    const ushort* __restrict__ s0, int n0,
    const ushort* __restrict__ s1, int n1,
    const ushort* __restrict__ Wp, const float* __restrict__ bias,
    void* __restrict__ outp, int H, int W)
{
    constexpr int NB = OCB / 16;
    const int n  = blockIdx.z;
    const int x0 = blockIdx.x * 16, y0 = blockIdx.y * 8;
    const int tid = threadIdx.x;
    const int wid = tid >> 6, lane = tid & 63;
    const int lm = lane & 15, kg = lane >> 4, k0 = kg * 8;
    const bool edge = (x0 == 0) || (x0 + 16 >= W) || (y0 == 0) || (y0 + 8 >= H);
    const int ntot = n0 + n1;
    const size_t HW = (size_t)H * W;

    const ushort* bptr[NKB];
    int bstr[NKB];
    bool bpad[NKB];
#pragma unroll
    for (int kb = 0; kb < NKB; kb++) {
        int gch = kb * 32 + k0;
        if (gch < n0)        { bptr[kb] = s0 + HW * (size_t)(n * n0) + gch;        bstr[kb] = n0; bpad[kb] = false; }
        else if (gch < ntot) { bptr[kb] = s1 + HW * (size_t)(n * n1) + (gch - n0); bstr[kb] = n1; bpad[kb] = false; }
        else                 { bptr[kb] = s0; bstr[kb] = 0; bpad[kb] = true; }
    }

    f32x4 acc[2][NB];
#pragma unroll
    for (int a = 0; a < 2; a++)
#pragma unroll
        for (int b = 0; b < NB; b++) acc[a][b] = (f32x4){0.f, 0.f, 0.f, 0.f};

#pragma unroll
    for (int kb = 0; kb < NKB; kb++) {
        bf16x8 areg[2][9];
#pragma unroll
        for (int ky = 0; ky < 3; ky++)
#pragma unroll
        for (int kx = 0; kx < 3; kx++) {
            const int t = ky * 3 + kx;
#pragma unroll
            for (int mt = 0; mt < 2; mt++) {
                int row = y0 + 2 * wid + mt + ky - 1;
                int xl  = x0 + lm + kx - 1;
                bf16x8 z = (bf16x8){0,0,0,0,0,0,0,0};
                if (!bpad[kb] && (!edge || (row >= 0 && row < H && xl >= 0 && xl < W)))
                    z = *(const bf16x8*)&bptr[kb][((size_t)(row * W + xl)) * bstr[kb]];
                areg[mt][t] = z;
            }
        }
#pragma unroll
        for (int t = 0; t < 9; t++) {
            bf16x8 wf[NB];
#pragma unroll
            for (int nb = 0; nb < NB; nb++)
                wf[nb] = *(const bf16x8*)&Wp[(((kb * 9) + t) * OCB + nb * 16 + lm) * 32 + k0];
#pragma unroll
            for (int nb = 0; nb < NB; nb++) {
#pragma unroll
                for (int mt = 0; mt < 2; mt++)
                    acc[mt][nb] = __builtin_amdgcn_mfma_f32_16x16x32_bf16(areg[mt][t], wf[nb], acc[mt][nb], 0, 0, 0);
            }
        }
    }

    if constexpr (OUTMODE == 0) {
        float* outf = (float*)outp;
#pragma unroll
        for (int mt = 0; mt < 2; mt++) {
            int y = y0 + 2 * wid + mt;
            int x = x0 + kg * 4;
#pragma unroll
            for (int nb = 0; nb < NB; nb++) {
                int oc = nb * 16 + lm;
                float bv = bias[oc];
                float r0 = acc[mt][nb][0] + bv, r1 = acc[mt][nb][1] + bv;
                float r2 = acc[mt][nb][2] + bv, r3 = acc[mt][nb][3] + bv;
                if (ACT == 1) { r0=fmaxf(r0,0.f); r1=fmaxf(r1,0.f); r2=fmaxf(r2,0.f); r3=fmaxf(r3,0.f); }
                if (ACT == 2) { r0=fast_tanh(r0); r1=fast_tanh(r1); r2=fast_tanh(r2); r3=fast_tanh(r3); }
                float4 o; o.x=r0; o.y=r1; o.z=r2; o.w=r3;
                *(float4*)&outf[(((size_t)n * OCB + oc) * H + y) * W + x] = o;
            }
        }
    } else {
        ushort* outb = (ushort*)outp;
        __shared__ ushort Ls[8 * 16 * OCB];
#pragma unroll
        for (int mt = 0; mt < 2; mt++) {
            int yy = 2 * wid + mt;
#pragma unroll
            for (int nb = 0; nb < NB; nb++) {
                int oc = nb * 16 + lm;
                float bv = bias[oc];
#pragma unroll
                for (int r = 0; r < 4; r++) {
                    float v = acc[mt][nb][r] + bv;
                    if (ACT == 1) v = fmaxf(v, 0.f);
                    if (ACT == 2) v = fast_tanh(v);
                    Ls[(yy * 16 + kg * 4 + r) * OCB + oc] = f2bf(v);
                }
            }
        }
        __syncthreads();
#pragma unroll
        for (int q = 0; q < NB; q++) {
            int off = tid * (NB * 8) + q * 8;
            int p = off / OCB, wv = off % OCB;
            int yy = p >> 4, xx = p & 15;
            *(bf16x8*)&outb[((size_t)((n * H + y0 + yy)) * W + x0 + xx) * OCB + wv] =
                *(const bf16x8*)&Ls[off];
        }
    }
}

// ---------------------------------------------------------------------------
__global__ __launch_bounds__(256) void pool_nhwc_k(
    const ushort* __restrict__ in, ushort* __restrict__ out, int C8, int Ho, int Wo)
{
    int idx = blockIdx.x * 256 + threadIdx.x;
    int total = 2 * Ho * Wo * C8;
    if (idx >= total) return;
    int s = idx % C8; int pix = idx / C8;
    int x = pix % Wo; int t = pix / Wo; int y = t % Ho; int n = t / Ho;
    int C = C8 * 8;
    const ushort* p = in + ((size_t)((n * 2 * Ho + 2 * y) * (2 * Wo) + 2 * x)) * C + s * 8;
    bf16x8 a = *(const bf16x8*)p;
    bf16x8 b = *(const bf16x8*)(p + C);
    bf16x8 c = *(const bf16x8*)(p + (size_t)(2 * Wo) * C);
    bf16x8 d = *(const bf16x8*)(p + (size_t)(2 * Wo) * C + C);
    ushort r[8];
#pragma unroll
    for (int j = 0; j < 8; j++) {
        float m = fmaxf(fmaxf(bf2f((ushort)a[j]), bf2f((ushort)b[j])),
                        fmaxf(bf2f((ushort)c[j]), bf2f((ushort)d[j])));
        r[j] = f2bf(m);
    }
    *(bf16x8*)&out[(size_t)pix * C + s * 8] = *(bf16x8*)r;
}

// ---------------------------------------------------------------------------
__global__ __launch_bounds__(256) void up_nhwc_k(
    const ushort* __restrict__ in, ushort* __restrict__ out, int C8, int Hi, int Wi)
{
    int Ho = Hi * 2, Wo = Wi * 2;
    int idx = blockIdx.x * 256 + threadIdx.x;
    int total = 2 * Ho * Wo * C8;
    if (idx >= total) return;
    int s = idx % C8; int pix = idx / C8;
    int x = pix % Wo; int t = pix / Wo; int y = t % Ho; int n = t / Ho;
    int C = C8 * 8;
    float sx = (x + 0.5f) * 0.5f - 0.5f;
    float sy = (y + 0.5f) * 0.5f - 0.5f;
    int ix0 = (int)floorf(sx), iy0 = (int)floorf(sy);
    float fx = sx - ix0, fy = sy - iy0;
    int ix1 = ix0 + 1, iy1 = iy0 + 1;
    ix0 = ix0 < 0 ? 0 : ix0;           iy0 = iy0 < 0 ? 0 : iy0;
    ix1 = ix1 > Wi - 1 ? Wi - 1 : ix1; iy1 = iy1 > Hi - 1 ? Hi - 1 : iy1;
    const ushort* base = in + (size_t)n * Hi * Wi * C + s * 8;
    bf16x8 v00 = *(const bf16x8*)&base[((size_t)iy0 * Wi + ix0) * C];
    bf16x8 v01 = *(const bf16x8*)&base[((size_t)iy0 * Wi + ix1) * C];
    bf16x8 v10 = *(const bf16x8*)&base[((size_t)iy1 * Wi + ix0) * C];
    bf16x8 v11 = *(const bf16x8*)&base[((size_t)iy1 * Wi + ix1) * C];
    ushort r[8];
#pragma unroll
    for (int j = 0; j < 8; j++) {
        float a = bf2f((ushort)v00[j]), b = bf2f((ushort)v01[j]);
        float c = bf2f((ushort)v10[j]), d = bf2f((ushort)v11[j]);
        float top = a + fx * (b - a);
        float bot = c + fx * (d - c);
        r[j] = f2bf(top + fy * (bot - top));
    }
    *(bf16x8*)&out[(size_t)pix * C + s * 8] = *(bf16x8*)r;
}

// ---------------------------------------------------------------------------
// NCHW fp32 16ch -> NHWC16 bf16
// ---------------------------------------------------------------------------
__global__ __launch_bounds__(256) void cvt16_k(
    const float* __restrict__ src, ushort* __restrict__ dst)
{
    int idx = blockIdx.x * 256 + threadIdx.x;
    int x = idx & 511, y = (idx >> 9) & 511, n = idx >> 18;
    const float* base = src + (size_t)n * 16 * 262144 + y * 512 + x;
    ushort vals[16];
#pragma unroll
    for (int c = 0; c < 16; c++) vals[c] = f2bf(base[(size_t)c * 262144]);
    ushort* d = dst + (size_t)idx * 16;
    *(bf16x8*)(d)     = *(bf16x8*)(vals);
    *(bf16x8*)(d + 8) = *(bf16x8*)(vals + 8);
}

// ---------------------------------------------------------------------------
// Direct VALU conv (fp32 in). OUTW 0: fp32 NCHW; 1: bf16 NHWC16; 2: bf16 NCHW.
// ---------------------------------------------------------------------------
template<int K, int OCB, int ACT, int PIX, int OUTW>
__global__ __launch_bounds__(256, 3) void conv_k(
    const float* __restrict__ src0, int c0,
    const float* __restrict__ src1, int c1,
    const float* __restrict__ src2, int c2,
    const float* __restrict__ src3, int c3,
    const float* __restrict__ w, const float* __restrict__ bias,
    void* __restrict__ outp, int H, int W, int OC, int ocChunks)
{
    constexpr int TW = 32, TH = 8 * PIX, P = K / 2;
    constexpr int TLW = TW + K - 1, TLH = TH + K - 1;
    constexpr int TLWP = (K == 3) ? 36 : 40;
    constexpr int CB = 4;
    __shared__ float tile[CB][TLH][TLWP];

    const int z   = blockIdx.z;
    const int n   = z / ocChunks;
    const int ocb = (z - n * ocChunks) * OCB;
    const int tx  = threadIdx.x & 31;
    const int ty  = threadIdx.x >> 5;
    const int x0  = blockIdx.x * TW, y0 = blockIdx.y * TH;
    const int Cin = c0 + c1 + c2 + c3;

    float acc[OCB][PIX];
#pragma unroll
    for (int i = 0; i < OCB; i++)
#pragma unroll
        for (int p = 0; p < PIX; p++) acc[i][p] = 0.f;

    int cgbase = 0;
#pragma unroll
    for (int s = 0; s < 4; s++) {
        const float* sp = (s == 0) ? src0 : (s == 1) ? src1 : (s == 2) ? src2 : src3;
        const int    cn = (s == 0) ? c0   : (s == 1) ? c1   : (s == 2) ? c2   : c3;
        for (int cb = 0; cb < cn; cb += CB) {
            const int nch = (cn - cb < CB) ? (cn - cb) : CB;
            __syncthreads();
            for (int idx = threadIdx.x; idx < nch * TLH * TLW; idx += 256) {
                int ch = idx / (TLH * TLW); int rem = idx - ch * (TLH * TLW);
                int r = rem / TLW, cc = rem - r * TLW;
                int gy = y0 + r - P, gx = x0 + cc - P;
                float vv = 0.f;
                if (gy >= 0 && gy < H && gx >= 0 && gx < W)
                    vv = sp[(size_t)(n * cn + cb + ch) * H * W + (size_t)gy * W + gx];
                tile[ch][r][cc] = vv;
            }
            __syncthreads();
            for (int c = 0; c < nch; c++) {
                float v[PIX + K - 1][K];
#pragma unroll
                for (int r = 0; r < PIX + K - 1; r++)
#pragma unroll
                    for (int cc = 0; cc < K; cc++)
                        v[r][cc] = tile[c][ty * PIX + r][tx + cc];
                const float* wc = w + ((size_t)ocb * Cin + (cgbase + cb + c)) * (K * K);
#pragma unroll
                for (int oc = 0; oc < OCB; oc++) {
                    const float* wo = wc + (size_t)oc * Cin * (K * K);
#pragma unroll
                    for (int ky = 0; ky < K; ky++)
#pragma unroll
                        for (int kx = 0; kx < K; kx++) {
                            float ww = wo[ky * K + kx];
#pragma unroll
                            for (int p = 0; p < PIX; p++)
                                acc[oc][p] = fmaf(ww, v[ky + p][kx], acc[oc][p]);
                        }
                }
            }
        }
        cgbase += cn;
    }

    const int xx = x0 + tx, yy = y0 + ty * PIX;
    if constexpr (OUTW == 0) {
        float* out = (float*)outp;
#pragma unroll
        for (int oc = 0; oc < OCB; oc++) {
            int o = ocb + oc;
            float b = bias[o];
#pragma unroll
            for (int p = 0; p < PIX; p++) {
                float r = acc[oc][p] + b;
                if (ACT == 1) r = fmaxf(r, 0.f);
                if (ACT == 2) r = tanhf(r);
                out[(((size_t)n * OC + o) * H + (yy + p)) * W + xx] = r;
            }
        }
    } else if constexpr (OUTW == 2) {
        ushort* ob = (ushort*)outp;
#pragma unroll
        for (int oc = 0; oc < OCB; oc++) {
            int o = ocb + oc;
            float b = bias[o];
#pragma unroll
            for (int p = 0; p < PIX; p++) {
                float r = acc[oc][p] + b;
                if (ACT == 1) r = fmaxf(r, 0.f);
                if (ACT == 2) r = tanhf(r);
                ob[(((size_t)n * OC + o) * H + (yy + p)) * W + xx] = f2bf(r);
            }
        }
    } else {
        ushort* ob = (ushort*)outp;
#pragma unroll
        for (int p = 0; p < PIX; p++) {
            ushort v16[16];
#pragma unroll
            for (int oc = 0; oc < OCB; oc++) {
                float r = acc[oc][p] + bias[oc];
                if (ACT == 1) r = fmaxf(r, 0.f);
                if (ACT == 2) r = tanhf(r);
                v16[oc] = f2bf(r);
            }
            ushort* d = &ob[(((size_t)n * H + (yy + p)) * W + xx) * 16];
            *(bf16x8*)d       = *(bf16x8*)v16;
            *(bf16x8*)(d + 8) = *(bf16x8*)(v16 + 8);
        }
    }
}

// ---------------------------------------------------------------------------
__global__ __launch_bounds__(256) void pool_k(
    const float* __restrict__ in, float* __restrict__ out, int NC, int H, int W)
{
    int H2 = H >> 1, W2 = W >> 1;
    int total = NC * H2 * W2;
    int idx = blockIdx.x * 256 + threadIdx.x;
    if (idx >= total) return;
    int x = idx % W2; int t = idx / W2; int y = t % H2; int q = t / H2;
    const float* p = in + ((size_t)q * H + 2 * y) * W + 2 * x;
    out[idx] = fmaxf(fmaxf(p[0], p[1]), fmaxf(p[W], p[W + 1]));
}

// ---------------------------------------------------------------------------
__global__ __launch_bounds__(256) void up_k(
    const float* __restrict__ in, float* __restrict__ out, int NC, int Hi, int Wi, int s)
{
    int Ho = Hi * s, Wo = Wi * s;
    int total = NC * Ho * Wo;
    int idx = blockIdx.x * 256 + threadIdx.x;
    if (idx >= total) return;
    int x = idx % Wo; int t = idx / Wo; int y = t % Ho; int q = t / Ho;
    float inv = 1.0f / (float)s;
    float sx = (x + 0.5f) * inv - 0.5f;
    float sy = (y + 0.5f) * inv - 0.5f;
    int ix0 = (int)floorf(sx), iy0 = (int)floorf(sy);
    float fx = sx - ix0, fy = sy - iy0;
    int ix1 = ix0 + 1, iy1 = iy0 + 1;
    ix0 = ix0 < 0 ? 0 : ix0;           iy0 = iy0 < 0 ? 0 : iy0;
    ix1 = ix1 > Wi - 1 ? Wi - 1 : ix1; iy1 = iy1 > Hi - 1 ? Hi - 1 : iy1;
    const float* p = in + (size_t)q * Hi * Wi;
    float v00 = p[(size_t)iy0 * Wi + ix0], v01 = p[(size_t)iy0 * Wi + ix1];
    float v10 = p[(size_t)iy1 * Wi + ix0], v11 = p[(size_t)iy1 * Wi + ix1];
    float top = v00 + fx * (v01 - v00);
    float bot = v10 + fx * (v11 - v10);
    out[idx] = top + fy * (bot - top);
}

// ---------------------------------------------------------------------------
__device__ __forceinline__ void scan_pair(const float a[8], float x1[8], float x2[8], int lane)
{
    float P = 1.f, Q1 = 0.f, Q2 = 0.f;
#pragma unroll
    for (int j = 0; j < 8; j++) {
        float av = a[j];
        Q1 = fmaf(av, Q1, (1.f - av) * x1[j]);
        Q2 = fmaf(av, Q2, (1.f - av) * x2[j]);
        P *= av;
    }
#pragma unroll
    for (int d = 1; d < 64; d <<= 1) {
        float Pp  = __shfl_up(P,  (unsigned)d);
        float Q1p = __shfl_up(Q1, (unsigned)d);
        float Q2p = __shfl_up(Q2, (unsigned)d);
        if (lane >= d) {
            Q1 = fmaf(P, Q1p, Q1);
            Q2 = fmaf(P, Q2p, Q2);
            P *= Pp;
        }
    }
    float h1in = __shfl_up(Q1, 1u);
    float h2in = __shfl_up(Q2, 1u);
    if (lane == 0) { h1in = 0.f; h2in = 0.f; }
    float s1 = h1in, s2 = h2in;
#pragma unroll
    for (int j = 0; j < 8; j++) {
        float av = a[j];
        s1 = fmaf(av, s1, (1.f - av) * x1[j]);
        s2 = fmaf(av, s2, (1.f - av) * x2[j]);
        x1[j] = s1; x2[j] = s2;
    }
}

// gates fp32 (r11 post-mortem: bf16 gates compound error); ms bf16.
__global__ __launch_bounds__(256) void scan_h_fused(
    const float* __restrict__ c9, const ushort* __restrict__ msb,
    float* __restrict__ hm)
{
    int gw   = (blockIdx.x * 256 + threadIdx.x) >> 6;
    int lane = threadIdx.x & 63;
    int y = gw & 511; int nc = gw >> 9; int c = nc & 15; int n = nc >> 4;
    const float* a1row = c9 + ((((size_t)n * 64 + c)      * 512 + y) << 9);
    const float* a2row = c9 + ((((size_t)n * 64 + 32 + c) * 512 + y) << 9);
    const size_t rowoff = (size_t)gw << 9;
    const ushort* ur = msb + rowoff;
    int t0 = lane << 3;

    float a1[8], a2[8], x1[8], x2[8];
    {
        float4 b0 = *(const float4*)(a1row + t0);
        float4 b1 = *(const float4*)(a1row + t0 + 4);
        a1[0]=b0.x; a1[1]=b0.y; a1[2]=b0.z; a1[3]=b0.w;
        a1[4]=b1.x; a1[5]=b1.y; a1[6]=b1.z; a1[7]=b1.w;
    }
    {
        float4 b0 = *(const float4*)(a2row + t0);
        float4 b1 = *(const float4*)(a2row + t0 + 4);
        a2[0]=b0.x; a2[1]=b0.y; a2[2]=b0.z; a2[3]=b0.w;
        a2[4]=b1.x; a2[5]=b1.y; a2[6]=b1.z; a2[7]=b1.w;
    }
    {
        bf16x8 v = *(const bf16x8*)(ur + t0);
#pragma unroll
        for (int j = 0; j < 8; j++) x1[j] = bf2f((ushort)v[j]);
    }
    {
        bf16x8 v = *(const bf16x8*)(ur + (504 - t0));   // elems 504-t0 .. 511-t0
#pragma unroll
        for (int j = 0; j < 8; j++) x2[j] = bf2f((ushort)v[7 - j]);
    }

    scan_pair(a1, x1, x2, lane);

    float r[8];
#pragma unroll
    for (int j = 0; j < 8; j++) r[j] = __shfl(x2[7 - j], 63 - lane);

    scan_pair(a2, x1, r, lane);

    float w0[4], w1[4];
#pragma unroll
    for (int j = 0; j < 4; j++) { w0[j] = fmaxf(x1[j], r[j]); w1[j] = fmaxf(x1[j+4], r[j+4]); }
    *(float4*)(hm + rowoff + t0)     = make_float4(w0[0], w0[1], w0[2], w0[3]);
    *(float4*)(hm + rowoff + t0 + 4) = make_float4(w1[0], w1[1], w1[2], w1[3]);
}

// ---------------------------------------------------------------------------
#define SV_DECODE \
    int g = blockIdx.x * 256 + threadIdx.x; \
    int x = g & 511; int nc = (g >> 9) & 31; int seg = g >> 14; \
    int c = nc & 15; int n = nc >> 4; int ys = seg << 6; (void)c; (void)n;

__global__ __launch_bounds__(256) void sv_a(
    const float* __restrict__ c9, const ushort* __restrict__ msb, float* __restrict__ SB)
{
    SV_DECODE
    const float* gx1 = c9 + (((size_t)n * 64 + c)      << 18) + x;
    const float* gy1 = c9 + (((size_t)n * 64 + 16 + c) << 18) + x;
    const ushort* u  = msb + ((size_t)nc << 18) + x;
    float P = 1.f, Q3 = 0.f, Q4 = 0.f;
    for (int i = 0; i < 64; i++) {
        int y = ys + i;
        float g3 = (y == 0) ? gy1[0] : gx1[(size_t)y << 9];
        float uf = bf2f(u[(size_t)y << 9]);
        float ub = bf2f(u[(size_t)(511 - y) << 9]);
        Q3 = fmaf(g3, Q3, (1.f - g3) * uf);
        Q4 = fmaf(g3, Q4, (1.f - g3) * ub);
        P *= g3;
    }
    SB[g] = P; SB[131072 + g] = Q3; SB[262144 + g] = Q4;
}

__global__ __launch_bounds__(256) void sv_b(
    float* __restrict__ c9, const ushort* __restrict__ msb,
    float* __restrict__ SB, ushort* __restrict__ h3buf)
{
    SV_DECODE
    const float* gx1 = c9 + (((size_t)n * 64 + c)      << 18) + x;
    const float* gy1 = c9 + (((size_t)n * 64 + 16 + c) << 18) + x;
    const float* gy2 = c9 + (((size_t)n * 64 + 48 + c) << 18) + x;
    float*       h4p = c9 + (((size_t)n * 64 + 32 + c) << 18) + x;
    const ushort* u  = msb + ((size_t)nc << 18) + x;
    ushort*      h3p = h3buf + ((size_t)nc << 18) + x;
    int gc = g & 16383;
    float s3 = 0.f, s4 = 0.f;
    for (int j = 0; j < seg; j++) {
        float Pj  = SB[j * 16384 + gc];
        float Q3j = SB[131072 + j * 16384 + gc];
        float Q4j = SB[262144 + j * 16384 + gc];
        s3 = fmaf(Pj, s3, Q3j);
        s4 = fmaf(Pj, s4, Q4j);
    }
    float P7 = 1.f, Q7 = 0.f;
    for (int i = 0; i < 64; i++) {
        int y = ys + i;
        float g3 = (y == 0) ? gy1[0] : gx1[(size_t)y << 9];
        float uf = bf2f(u[(size_t)y << 9]);
        float ub = bf2f(u[(size_t)(511 - y) << 9]);
        s3 = fmaf(g3, s3, (1.f - g3) * uf);
        s4 = fmaf(g3, s4, (1.f - g3) * ub);
        h3p[(size_t)y << 9] = f2bf(s3);
        h4p[(size_t)y << 9] = s4;
        float g7 = gy2[(size_t)y << 9];
        Q7 = fmaf(g7, Q7, (1.f - g7) * s3);
        P7 *= g7;
    }
    SB[393216 + g] = P7; SB[524288 + g] = Q7;
}

__global__ __launch_bounds__(256) void sv_c(
    const float* __restrict__ c9, const ushort* __restrict__ h3buf,
    float* __restrict__ SB, float* __restrict__ hm)
{
    SV_DECODE
    const float* gy2 = c9 + (((size_t)n * 64 + 48 + c) << 18) + x;
    const float* h4p = c9 + (((size_t)n * 64 + 32 + c) << 18) + x;
    const ushort* h3p = h3buf + ((size_t)nc << 18) + x;
    float*        o   = hm + ((size_t)nc << 18) + x;
    int gc = g & 16383;
    float s7 = 0.f;
    for (int j = 0; j < seg; j++) {
        float Pj = SB[393216 + j * 16384 + gc];
        float Qj = SB[524288 + j * 16384 + gc];
        s7 = fmaf(Pj, s7, Qj);
    }
    float P8 = 1.f, Q8 = 0.f;
    for (int i = 0; i < 64; i++) {
        int y = ys + i;
        float g7 = gy2[(size_t)y << 9];
        float hv = bf2f(h3p[(size_t)y << 9]);
        s7 = fmaf(g7, s7, (1.f - g7) * hv);
        o[(size_t)y << 9] = fmaxf(o[(size_t)y << 9], s7);
        float u8 = h4p[(size_t)(511 - y) << 9];
        Q8 = fmaf(g7, Q8, (1.f - g7) * u8);
        P8 *= g7;
    }
    SB[655360 + g] = P8; SB[786432 + g] = Q8;
}

__global__ __launch_bounds__(256) void sv_d(
    const float* __restrict__ c9, const float* __restrict__ SB, float* __restrict__ hm)
{
    SV_DECODE
    const float* gy2 = c9 + (((size_t)n * 64 + 48 + c) << 18) + x;
    const float* h4p = c9 + (((size_t)n * 64 + 32 + c) << 18) + x;
    float*       o   = hm + ((size_t)nc << 18) + x;
    int gc = g & 16383;
    float s8 = 0.f;
    for (int j = 0; j < seg; j++) {
        float Pj = SB[655360 + j * 16384 + gc];
        float Qj = SB[786432 + j * 16384 + gc];
        s8 = fmaf(Pj, s8, Qj);
    }
    for (int i = 0; i < 64; i++) {
        int y = ys + i;
        float g7 = gy2[(size_t)y << 9];
        float u8 = h4p[(size_t)(511 - y) << 9];
        s8 = fmaf(g7, s8, (1.f - g7) * u8);
        o[(size_t)y << 9] = fmaxf(o[(size_t)y << 9], s8);
    }
}

// ---------------------------------------------------------------------------
extern "C" void kernel_launch(void* const* d_in, const int* in_sizes, int n_in,
                              void* d_out, int out_size, void* d_ws, size_t ws_size,
                              hipStream_t stream)
{
    const float* x    = (const float*)d_in[0];
    const float* w_s1 = (const float*)d_in[1];  const float* b_s1 = (const float*)d_in[2];
    const float* w_mc = (const float*)d_in[3];  const float* b_mc = (const float*)d_in[4];
    const float* w2   = (const float*)d_in[5];  const float* b2   = (const float*)d_in[6];
    const float* w3   = (const float*)d_in[7];  const float* b3   = (const float*)d_in[8];
    const float* w4   = (const float*)d_in[9];  const float* b4   = (const float*)d_in[10];
    const float* w5   = (const float*)d_in[11]; const float* b5   = (const float*)d_in[12];
    const float* w6   = (const float*)d_in[13]; const float* b6   = (const float*)d_in[14];
    const float* w6s  = (const float*)d_in[15]; const float* b6s  = (const float*)d_in[16];
    const float* w7   = (const float*)d_in[17]; const float* b7   = (const float*)d_in[18];
    const float* w8   = (const float*)d_in[19]; const float* b8   = (const float*)d_in[20];
    const float* w9   = (const float*)d_in[21]; const float* b9   = (const float*)d_in[22];
    const float* w10  = (const float*)d_in[23]; const float* b10  = (const float*)d_in[24];
    const float* w11  = (const float*)d_in[25]; const float* b11  = (const float*)d_in[26];
    float* out = (float*)d_out;
    float* ws  = (float*)d_ws;

    const size_t NEEDED = 60817408ull * 4ull;   // 232 MiB (verified r2-r10)
    if (ws_size < NEEDED) return;

    // -------- global regions --------
    ushort* MSb  = (ushort*)ws;                 // [2,16,512,512] bf16 ms (region reserved as r10)
    float*  C9   = ws + 8388608;                // [2,64,512,512] fp32 gates (+h4 fp32)
    float*  H3REG = ws + 41943040;              // u2/u3/u4 fp32 -> h3 bf16 -> A10
    float*  AR    = ws + 50331648;              // arena, 10,485,760 floats

    // packed weights (permanent, arena head)
    ushort* WREG = (ushort*)AR;
    ushort* wp3  = WREG + 0;      ushort* wp4  = WREG + 9216;
    ushort* wp5  = WREG + 18432;  ushort* wp6  = WREG + 27648;
    ushort* wp6s = WREG + 46080;  ushort* wp7  = WREG + 82944;
    ushort* wp8  = WREG + 110592; ushort* wp9  = WREG + 119808;
    ushort* wp10 = WREG + 138240; ushort* wp11 = WREG + 156672;

    // phase A (fp32 multi-scale)
    ushort* C2b = (ushort*)(AR + 163840);   // [2,512,512,16] bf16, live -> gconv9
    float* s1f = AR + 4358144;
    float* s2f = AR + 5931008;
    float* s3f = AR + 6324224;
    float* s4f = AR + 6422528;
    float* u2  = H3REG + 0;
    float* u3  = H3REG + 1572864;
    float* u4  = H3REG + 3145728;
    // phase B (NHWC bf16 encoder/decoder, liveness-packed)
    ushort* p2    = (ushort*)(AR + 4358144);
    ushort* c3    = (ushort*)(AR + 5406720);
    ushort* p3    = (ushort*)(AR + 7503872);
    ushort* c4    = (ushort*)(AR + 8028160);
    ushort* p4    = (ushort*)(AR + 8552448);
    ushort* c5    = (ushort*)(AR + 8683520);
    ushort* p5    = (ushort*)(AR + 8814592);
    ushort* c6    = (ushort*)(AR + 8847360);
    ushort* u6    = (ushort*)(AR + 8912896);
    ushort* t6    = (ushort*)(AR + 9175040);
    ushort* c6re  = (ushort*)(AR + 9437184);
    ushort* c7pre = (ushort*)(AR + 7503872);
    ushort* c7    = (ushort*)(AR + 8028160);
    ushort* c8pre = (ushort*)(AR + 4358144);
    ushort* c8b   = (ushort*)(AR + 5406720);
    // scans / head
    float* SB  = AR + 163840;
    float* HM  = AR + 1081344;
    ushort* H3u = (ushort*)H3REG;      // h3 bf16 (after u2..u4 dead)
    ushort* A10 = (ushort*)H3REG;      // after h3 dead
    ushort* A11 = (ushort*)C9;         // after gates dead

    auto cdiv = [](int a, int b) { return (a + b - 1) / b; };

    // ---- pack all weights ----
    packw_k<<<36,256,0,stream>>>(w3,  wp3,  32, 32, 16, 1);
    packw_k<<<36,256,0,stream>>>(w4,  wp4,  32, 32, 32, 1);
    packw_k<<<36,256,0,stream>>>(w5,  wp5,  32, 32, 32, 1);
    packw_k<<<72,256,0,stream>>>(w6,  wp6,  64, 64, 32, 1);
    packw_k<<<144,256,0,stream>>>(w6s, wp6s, 64, 64, 64, 2);
    packw_k<<<108,256,0,stream>>>(w7,  wp7,  32, 32, 96, 3);
    packw_k<<<36,256,0,stream>>>(w8,  wp8,  16, 16, 64, 2);
    packw_k<<<72,256,0,stream>>>(w9,  wp9,  64, 64, 32, 1);
    packw_k<<<72,256,0,stream>>>(w10, wp10, 64, 64, 16, 1);
    packw_k<<<36,256,0,stream>>>(w11, wp11, 16, 3,  64, 2);

    // ---- phase A: w2 (bf16 NHWC out) + multi-scale (fp32 compute) ----
    conv_k<5,16,1,2,1><<<dim3(16,32,2),256,0,stream>>>(x,3,nullptr,0,nullptr,0,nullptr,0,
                                                       w2,b2, C2b, 512,512,16,1);
    conv_k<3,3,0,2,0><<<dim3(16,32,2),256,0,stream>>>(x,3,nullptr,0,nullptr,0,nullptr,0,
                                                      w_s1,b_s1, s1f, 512,512,3,1);
    pool_k<<<cdiv(2*3*256*256,256),256,0,stream>>>(s1f, s2f, 6, 512, 512);
    pool_k<<<cdiv(2*3*128*128,256),256,0,stream>>>(s2f, s3f, 6, 256, 256);
    pool_k<<<cdiv(2*3*64*64,  256),256,0,stream>>>(s3f, s4f, 6, 128, 128);
    up_k<<<6144,256,0,stream>>>(s2f, u2, 6, 256, 256, 2);
    up_k<<<6144,256,0,stream>>>(s3f, u3, 6, 128, 128, 4);
    up_k<<<6144,256,0,stream>>>(s4f, u4, 6, 64, 64, 8);
    conv_k<3,16,0,2,2><<<dim3(16,32,2),256,0,stream>>>(s1f,3,u2,3,u3,3,u4,3,
                                                       w_mc,b_mc, MSb, 512,512,16,1);

    // ---- encoder / decoder (NHWC bf16, MFMA) ----
    pool_nhwc_k<<<1024,256,0,stream>>>(C2b, p2, 2, 256, 256);
    gconv_k<32,1,1,1><<<dim3(16,32,2),256,0,stream>>>(p2,16,nullptr,0, wp3,b3, c3, 256,256);
    pool_nhwc_k<<<512,256,0,stream>>>(c3, p3, 4, 128, 128);
    gconv_k<32,1,1,1><<<dim3(8,16,2),256,0,stream>>>(p3,32,nullptr,0, wp4,b4, c4, 128,128);
    pool_nhwc_k<<<128,256,0,stream>>>(c4, p4, 4, 64, 64);
    gconv_k<32,1,1,1><<<dim3(4,8,2),256,0,stream>>>(p4,32,nullptr,0, wp5,b5, c5, 64,64);
    pool_nhwc_k<<<32,256,0,stream>>>(c5, p5, 4, 32, 32);
    gconv_k<64,1,1,1><<<dim3(2,4,2),256,0,stream>>>(p5,32,nullptr,0, wp6,b6, c6, 32,32);
    up_nhwc_k<<<256,256,0,stream>>>(c6, u6, 8, 32, 32);
    gconv_k<64,2,1,1><<<dim3(4,8,2),256,0,stream>>>(u6,64,nullptr,0, wp6s,b6s, t6, 64,64);
    up_nhwc_k<<<1024,256,0,stream>>>(t6, c6re, 8, 64, 64);
    gconv_k<32,3,1,1><<<dim3(8,16,2),256,0,stream>>>(c6re,64, c4,32, wp7,b7, c7pre, 128,128);
    up_nhwc_k<<<2048,256,0,stream>>>(c7pre, c7, 4, 128, 128);
    gconv_k<16,2,1,1><<<dim3(16,32,2),256,0,stream>>>(c7,32, c3,32, wp8,b8, c8pre, 256,256);
    up_nhwc_k<<<4096,256,0,stream>>>(c8pre, c8b, 2, 256, 256);
    // c9 -> fp32 NCHW gates (r11 lesson: bf16 gates compound scan error)
    gconv_mr<64,1,2,0><<<dim3(32,32,2),256,0,stream>>>(c8b,16, C2b,16, wp9,b9, C9, 512,512);

    // ---- linear recurrence scans (fp32 gates/compute; bf16 ms/h3) ----
    scan_h_fused<<<4096,256,0,stream>>>(C9, MSb, HM);
    sv_a<<<512,256,0,stream>>>(C9, MSb, SB);
    sv_b<<<512,256,0,stream>>>(C9, MSb, SB, H3u);
    sv_c<<<512,256,0,stream>>>(C9, H3u, SB, HM);
    sv_d<<<512,256,0,stream>>>(C9, SB, HM);

    // ---- head: c10 + w11 (MFMA, multi-row) ----
    cvt16_k<<<2048,256,0,stream>>>(HM, A10);
    gconv_mr<64,1,1,1><<<dim3(32,32,2),256,0,stream>>>(A10,16,nullptr,0, wp10,b10, A11, 512,512);
    gconv11_mr<<<dim3(32,32,2),256,0,stream>>>(A11, wp11, b11, out);
    (void)in_sizes; (void)n_in; (void)out_size; (void)ws_size;
}